// Round 1
// baseline (567.398 us; speedup 1.0000x reference)
//
#include <hip/hip_runtime.h>

// EdgeBlock: out[e] = relu(concat(edges[e], nodes[send[e]], nodes[recv[e]], gg[batch[e]]) @ W1 + b1) @ W2 + b2
// E=1.6M, in=112 (pad 128), hidden=64, out=32. ALL float tensors are float32; indices int32; out float32.
//
// Strategy: transposed MFMA GEMMs, 16 edges per wave, no LDS.
//   Gather x^T as f32 (coalesced float8 per lane), convert to bf16 in-register (v_perm pack, round-half-up).
//   GEMM1: h^T = W1^T @ x^T (4x MFMA K=128); GEMM2: o^T = W2^T @ h^T, B-frags built via ds_bpermute.
//   Epilogue bias adds in f32; output stored as f32 (16B stores, coalesced).
//
// R1 change (latency theory): counters showed dur=219us with HBM 26%, MfmaUtil 5.9%, VALU 17%,
//   traffic already minimal (460MB) -> latency-bound on the idx->gather dependent chain.
//   Software pipeline: exact trip count NITER=10 per wave; while group k computes, group k+1's
//   x^T gathers and group k+2's indices are in flight. Double-buffered gather regs (+32 VGPR).

typedef __attribute__((ext_vector_type(8))) short short8;
typedef __attribute__((ext_vector_type(4))) float floatx4;
typedef __attribute__((ext_vector_type(8))) float floatx8;
typedef __attribute__((ext_vector_type(4))) int intx4;

#define E_TOTAL 1600000
#define NGROUPS (E_TOTAL / 16)      // 100000
#define NWAVES  10000               // 2500 blocks x 4 waves; divides NGROUPS exactly
#define NITER   (NGROUPS / NWAVES)  // 10 groups per wave, uniform
#define ESTRIDE (NWAVES * 16)       // 160000 edges between a wave's consecutive groups

// pack two f32 -> (bf16(hi)<<16)|bf16(lo), round-half-up (+0x8000 then take high 16)
__device__ inline unsigned int pack_bf(float lo, float hi) {
    unsigned int a = __builtin_bit_cast(unsigned int, lo) + 0x8000u;
    unsigned int b = __builtin_bit_cast(unsigned int, hi) + 0x8000u;
    return __builtin_amdgcn_perm(b, a, 0x07060302);  // {b.hi16, a.hi16}
}

__device__ inline short8 cvt8(floatx8 f) {
    intx4 r;
    r[0] = (int)pack_bf(f[0], f[1]);
    r[1] = (int)pack_bf(f[2], f[3]);
    r[2] = (int)pack_bf(f[4], f[5]);
    r[3] = (int)pack_bf(f[6], f[7]);
    return __builtin_bit_cast(short8, r);
}

__global__ __launch_bounds__(256) void edge_mlp(
    const float* __restrict__ nodes,   // [50000][32]
    const float* __restrict__ edges,   // [E][32]
    const float* __restrict__ gg,      // [64][16]
    const int* __restrict__ send,
    const int* __restrict__ recv,
    const int* __restrict__ batch,
    const float* __restrict__ W1,      // [112][64]
    const float* __restrict__ b1,      // [64]
    const float* __restrict__ W2,      // [64][32]
    const float* __restrict__ b2,      // [32]
    float* __restrict__ out)           // [E][32]
{
    const int lane = threadIdx.x & 63;
    const int wid  = (int)((blockIdx.x * blockDim.x + threadIdx.x) >> 6);
    const int q = lane >> 4;     // quad: selects k-block of 8
    const int c = lane & 15;     // A-layout: row m; B-layout: col n; C-layout: col

    // ---- W1^T A-fragments: w1f[s][t], element j: A[m=c][k=q*8+j] of K-step s, hid-tile t
    short8 w1f[4][4];
#pragma unroll
    for (int s = 0; s < 4; ++s)
#pragma unroll
        for (int t = 0; t < 4; ++t) {
            floatx8 f;
            const int hid = t * 16 + c;
#pragma unroll
            for (int j = 0; j < 8; ++j) {
                const int k = s * 32 + q * 8 + j;
                f[j] = (k < 112) ? W1[k * 64 + hid] : 0.0f;
            }
            w1f[s][t] = cvt8(f);
        }
    // ---- W2^T A-fragments
    short8 w2f[2][2];
#pragma unroll
    for (int s2 = 0; s2 < 2; ++s2)
#pragma unroll
        for (int u = 0; u < 2; ++u) {
            floatx8 f;
            const int od = u * 16 + c;
#pragma unroll
            for (int j = 0; j < 8; ++j)
                f[j] = W2[(s2 * 32 + q * 8 + j) * 32 + od];
            w2f[s2][u] = cvt8(f);
        }
    // ---- biases (f32, added in epilogue), C-layout row = tile*16 + q*4 + r
    float b1v[4][4], b2v[2][4];
#pragma unroll
    for (int t = 0; t < 4; ++t)
#pragma unroll
        for (int r = 0; r < 4; ++r) b1v[t][r] = b1[t * 16 + q * 4 + r];
#pragma unroll
    for (int u = 0; u < 2; ++u)
#pragma unroll
        for (int r = 0; r < 4; ++r) b2v[u][r] = b2[u * 16 + q * 4 + r];

    // bpermute source-lane byte indices for the C->B quad shuffle
    const int idx_lo = (((q & 1) * 2) * 16 + c) * 4;  // m = 0,1
    const int idx_hi = idx_lo + 64;                   // m = 2,3
    const bool want_hi_tile = (q >= 2);

    // compute + store one group whose gathered x^T (f32) is in f0..f3
    auto compute_group = [&](int e_, floatx8 f0, floatx8 f1, floatx8 f2, floatx8 f3) {
        short8 bx0 = cvt8(f0), bx1 = cvt8(f1), bx2 = cvt8(f2), bx3 = cvt8(f3);

        // GEMM1: h^T tiles t=0..3 (hidden row t*16+q*4+r, col = edge c)
        floatx4 acc[4];
#pragma unroll
        for (int t = 0; t < 4; ++t) {
            floatx4 a = {0.f, 0.f, 0.f, 0.f};
            a = __builtin_amdgcn_mfma_f32_16x16x32_bf16(w1f[0][t], bx0, a, 0, 0, 0);
            a = __builtin_amdgcn_mfma_f32_16x16x32_bf16(w1f[1][t], bx1, a, 0, 0, 0);
            a = __builtin_amdgcn_mfma_f32_16x16x32_bf16(w1f[2][t], bx2, a, 0, 0, 0);
            a = __builtin_amdgcn_mfma_f32_16x16x32_bf16(w1f[3][t], bx3, a, 0, 0, 0);
            acc[t] = a;
        }

        // bias + relu + pack
        unsigned int pk[4][2];
#pragma unroll
        for (int t = 0; t < 4; ++t) {
            float v0 = fmaxf(acc[t][0] + b1v[t][0], 0.f);
            float v1 = fmaxf(acc[t][1] + b1v[t][1], 0.f);
            float v2 = fmaxf(acc[t][2] + b1v[t][2], 0.f);
            float v3 = fmaxf(acc[t][3] + b1v[t][3], 0.f);
            pk[t][0] = pack_bf(v0, v1);
            pk[t][1] = pack_bf(v2, v3);
        }

        // GEMM2: o^T = W2^T @ h^T ; B-frags from pk via ds_bpermute
        floatx4 acc2[2];
        acc2[0] = floatx4{0.f, 0.f, 0.f, 0.f};
        acc2[1] = floatx4{0.f, 0.f, 0.f, 0.f};
#pragma unroll
        for (int s2 = 0; s2 < 2; ++s2) {
            intx4 br;
#pragma unroll
            for (int m = 0; m < 4; ++m) {
                const int idx = (m >= 2) ? idx_hi : idx_lo;
                int vlo = __builtin_amdgcn_ds_bpermute(idx, (int)pk[2 * s2][m & 1]);
                int vhi = __builtin_amdgcn_ds_bpermute(idx, (int)pk[2 * s2 + 1][m & 1]);
                br[m] = want_hi_tile ? vhi : vlo;
            }
            short8 bB = __builtin_bit_cast(short8, br);
            acc2[0] = __builtin_amdgcn_mfma_f32_16x16x32_bf16(w2f[s2][0], bB, acc2[0], 0, 0, 0);
            acc2[1] = __builtin_amdgcn_mfma_f32_16x16x32_bf16(w2f[s2][1], bB, acc2[1], 0, 0, 0);
        }

        // store f32: lane holds out dims u*16+q*4+{0..3} of edge e_ -> 16B stores
#pragma unroll
        for (int u = 0; u < 2; ++u) {
            floatx4 o;
            o[0] = acc2[u][0] + b2v[u][0];
            o[1] = acc2[u][1] + b2v[u][1];
            o[2] = acc2[u][2] + b2v[u][2];
            o[3] = acc2[u][3] + b2v[u][3];
            *(floatx4*)(out + (size_t)e_ * 32 + u * 16 + q * 4) = o;
        }
    };

    // ---- software-pipelined main loop: exactly NITER groups per wave ----
    int e = wid * 16 + c;

    // prologue: indices+gathers for group 0, indices for group 1
    int seB = send[e], reB = recv[e], beB = batch[e];
    floatx8 a0 = *(const floatx8*)(edges + (size_t)e * 32 + q * 8);
    floatx8 a1 = *(const floatx8*)(nodes + (size_t)seB * 32 + q * 8);
    floatx8 a2 = *(const floatx8*)(nodes + (size_t)reB * 32 + q * 8);
    floatx8 a3 = {0.f, 0.f, 0.f, 0.f, 0.f, 0.f, 0.f, 0.f};
    if (q < 2) a3 = *(const floatx8*)(gg + (size_t)beB * 16 + q * 8);
    {
        const int e1 = e + ESTRIDE;
        seB = send[e1]; reB = recv[e1]; beB = batch[e1];
    }

#pragma unroll 2
    for (int k = 0; k < NITER - 1; ++k) {
        const int en = e + ESTRIDE;
        // issue group k+1's gathers (its indices are already resident in seB/reB/beB)
        floatx8 n0 = *(const floatx8*)(edges + (size_t)en * 32 + q * 8);
        floatx8 n1 = *(const floatx8*)(nodes + (size_t)seB * 32 + q * 8);
        floatx8 n2 = *(const floatx8*)(nodes + (size_t)reB * 32 + q * 8);
        floatx8 n3 = {0.f, 0.f, 0.f, 0.f, 0.f, 0.f, 0.f, 0.f};
        if (q < 2) n3 = *(const floatx8*)(gg + (size_t)beB * 16 + q * 8);
        // issue group k+2's index loads (clamped to a valid addr on the final trip; value unused)
        int e2 = en + ESTRIDE;
        if (e2 >= E_TOTAL) e2 = e;
        seB = send[e2]; reB = recv[e2]; beB = batch[e2];

        // compute group k while the above are in flight
        compute_group(e, a0, a1, a2, a3);

        // rotate pipeline registers
        a0 = n0; a1 = n1; a2 = n2; a3 = n3;
        e = en;
    }
    // epilogue: last group, nothing left to prefetch
    compute_group(e, a0, a1, a2, a3);
}

extern "C" void kernel_launch(void* const* d_in, const int* in_sizes, int n_in,
                              void* d_out, int out_size, void* d_ws, size_t ws_size,
                              hipStream_t stream) {
    (void)in_sizes; (void)n_in; (void)out_size; (void)d_ws; (void)ws_size;
    const float* nodes = (const float*)d_in[0];
    const float* edges = (const float*)d_in[1];
    const float* gg    = (const float*)d_in[2];
    const int* send  = (const int*)d_in[3];
    const int* recv  = (const int*)d_in[4];
    const int* batch = (const int*)d_in[5];
    const float* W1 = (const float*)d_in[6];
    const float* b1 = (const float*)d_in[7];
    const float* W2 = (const float*)d_in[8];
    const float* b2 = (const float*)d_in[9];
    float* out = (float*)d_out;

    const int blocks = NWAVES / 4;   // 2500 blocks x 4 waves = 10000 waves -> 10 groups/wave exact
    edge_mlp<<<blocks, 256, 0, stream>>>(nodes, edges, gg, send, recv, batch,
                                         W1, b1, W2, b2, out);
}

// Round 2
// 504.198 us; speedup vs baseline: 1.1253x; 1.1253x over previous
//
#include <hip/hip_runtime.h>

// EdgeBlock: out[e] = relu(concat(edges[e], nodes[send[e]], nodes[recv[e]], gg[batch[e]]) @ W1 + b1) @ W2 + b2
// E=1.6M, in=112 (pad 128), hidden=64, out=32. float32 tensors, int32 indices, float32 out.
//
// Strategy: transposed MFMA GEMMs, 16 edges per wave. Weights resident in VGPRs (bf16 frags).
//   GEMM1: h^T = W1^T @ x^T (4x MFMA K=128, b1 folded into W1 row 112 vs constant-1 feature);
//   GEMM2: o^T = W2^T @ h^T, B-frags built via ds_bpermute. f32 epilogue + coalesced 16B stores.
//
// R2 change (register-free prefetch): R1 showed ILP-via-VGPR double buffering crosses the 128-reg
//   cliff (144 regs -> occupancy halved -> 313us). This version prefetches the next group's x^T
//   gathers via global_load_lds DMA into a PRIVATE per-wave 8KB LDS FIFO (no barriers, no VGPR cost),
//   with counted s_waitcnt vmcnt(3) so idx loads/stores stay in flight. Index loads prefetched depth-2.
//   Target: <=128 VGPR (launch_bounds(256,4)) with full latency overlap.

typedef __attribute__((ext_vector_type(8))) short short8;
typedef __attribute__((ext_vector_type(4))) float floatx4;
typedef __attribute__((ext_vector_type(8))) float floatx8;
typedef __attribute__((ext_vector_type(4))) int intx4;

#define E_TOTAL 1600000
#define NWAVES  10000               // 2500 blocks x 4 waves
#define NITER   10                  // groups per wave, exact: NWAVES*NITER*16 == E_TOTAL
#define ESTRIDE (NWAVES * 16)

// pack two f32 -> (bf16(hi)<<16)|bf16(lo), round-half-up (+0x8000 then take high 16)
__device__ inline unsigned int pack_bf(float lo, float hi) {
    unsigned int a = __builtin_bit_cast(unsigned int, lo) + 0x8000u;
    unsigned int b = __builtin_bit_cast(unsigned int, hi) + 0x8000u;
    return __builtin_amdgcn_perm(b, a, 0x07060302);  // {b.hi16, a.hi16}
}

__device__ inline short8 cvt8(floatx8 f) {
    intx4 r;
    r[0] = (int)pack_bf(f[0], f[1]);
    r[1] = (int)pack_bf(f[2], f[3]);
    r[2] = (int)pack_bf(f[4], f[5]);
    r[3] = (int)pack_bf(f[6], f[7]);
    return __builtin_bit_cast(short8, r);
}

__device__ inline short8 cvt8p(floatx4 lo, floatx4 hi) {
    intx4 r;
    r[0] = (int)pack_bf(lo[0], lo[1]);
    r[1] = (int)pack_bf(lo[2], lo[3]);
    r[2] = (int)pack_bf(hi[0], hi[1]);
    r[3] = (int)pack_bf(hi[2], hi[3]);
    return __builtin_bit_cast(short8, r);
}

// async DMA: 16B per lane, per-lane GLOBAL src address, wave-uniform LDS dest (+lane*16 in HW)
__device__ inline void glds16(const void* g, void* l) {
    __builtin_amdgcn_global_load_lds(
        (const __attribute__((address_space(1))) void*)g,
        (__attribute__((address_space(3))) void*)l,
        16, 0, 0);
}

__global__ __launch_bounds__(256, 4) void edge_mlp(
    const float* __restrict__ nodes,   // [50000][32]
    const float* __restrict__ edges,   // [E][32]
    const float* __restrict__ gg,      // [64][16]
    const int* __restrict__ send,
    const int* __restrict__ recv,
    const int* __restrict__ batch,
    const float* __restrict__ W1,      // [112][64]
    const float* __restrict__ b1,      // [64]
    const float* __restrict__ W2,      // [64][32]
    const float* __restrict__ b2,      // [32]
    float* __restrict__ out)           // [E][32]
{
    const int lane = threadIdx.x & 63;
    const int wid  = (int)((blockIdx.x * blockDim.x + threadIdx.x) >> 6);
    const int q = lane >> 4;     // quad: selects k-block of 8
    const int c = lane & 15;     // A-layout: row m; B-layout: col n; C-layout: col

    // per-wave private 8KB LDS FIFO: 8 slots of 1KB; slot s holds lane L's 16B at s*1024 + L*16
    __shared__ alignas(16) float smem[4 * 2048];
    float* wbuf = &smem[(threadIdx.x >> 6) * 2048];

    // ---- W1^T A-fragments, b1 FOLDED at k==112 (pairs with constant-1 feature in x-pad):
    //      w1f[s][t] elem j = A[m=c][k=q*8+j] of K-step s, hid-tile t
    short8 w1f[4][4];
#pragma unroll
    for (int s = 0; s < 4; ++s)
#pragma unroll
        for (int t = 0; t < 4; ++t) {
            floatx8 f;
            const int hid = t * 16 + c;
#pragma unroll
            for (int j = 0; j < 8; ++j) {
                const int k = s * 32 + q * 8 + j;
                f[j] = (k < 112) ? W1[k * 64 + hid] : ((k == 112) ? b1[hid] : 0.0f);
            }
            w1f[s][t] = cvt8(f);
        }
    // ---- W2^T A-fragments
    short8 w2f[2][2];
#pragma unroll
    for (int s2 = 0; s2 < 2; ++s2)
#pragma unroll
        for (int u = 0; u < 2; ++u) {
            floatx8 f;
            const int od = u * 16 + c;
#pragma unroll
            for (int j = 0; j < 8; ++j)
                f[j] = W2[(s2 * 32 + q * 8 + j) * 32 + od];
            w2f[s2][u] = cvt8(f);
        }
    // ---- b2 (f32, epilogue), C-layout row = u*16 + q*4 + r
    float b2v[2][4];
#pragma unroll
    for (int u = 0; u < 2; ++u)
#pragma unroll
        for (int r = 0; r < 4; ++r) b2v[u][r] = b2[u * 16 + q * 4 + r];

    // bpermute source-lane byte indices for the C->B quad shuffle
    const int idx_lo = (((q & 1) * 2) * 16 + c) * 4;  // m = 0,1
    const int idx_hi = idx_lo + 64;                   // m = 2,3
    const bool want_hi_tile = (q >= 2);

    // issue the 8 DMA loads staging group (per-lane edge eb)'s x^T into the wave FIFO
    auto prefetch = [&](int eb, int s_, int r_, int b_) {
        glds16(edges + (size_t)eb * 32 + q * 8,      wbuf + 0 * 256);
        glds16(edges + (size_t)eb * 32 + q * 8 + 4,  wbuf + 1 * 256);
        glds16(nodes + (size_t)s_ * 32 + q * 8,      wbuf + 2 * 256);
        glds16(nodes + (size_t)s_ * 32 + q * 8 + 4,  wbuf + 3 * 256);
        glds16(nodes + (size_t)r_ * 32 + q * 8,      wbuf + 4 * 256);
        glds16(nodes + (size_t)r_ * 32 + q * 8 + 4,  wbuf + 5 * 256);
        // gg: only q<2 lanes carry real data; q>=2 lanes read a harmless in-bounds addr (fixed on readback)
        glds16(gg + (size_t)b_ * 16 + (q & 1) * 8,      wbuf + 6 * 256);
        glds16(gg + (size_t)b_ * 16 + (q & 1) * 8 + 4,  wbuf + 7 * 256);
    };

    // read group from FIFO, convert to bf16 B-fragments (frees f32 temps before next prefetch)
    auto load_cvt = [&](short8& bx0, short8& bx1, short8& bx2, short8& bx3) {
        const float* p = wbuf + lane * 4;
        floatx4 l0 = *(const floatx4*)(p + 0 * 256);
        floatx4 h0 = *(const floatx4*)(p + 1 * 256);
        floatx4 l1 = *(const floatx4*)(p + 2 * 256);
        floatx4 h1 = *(const floatx4*)(p + 3 * 256);
        floatx4 l2 = *(const floatx4*)(p + 4 * 256);
        floatx4 h2 = *(const floatx4*)(p + 5 * 256);
        floatx4 l3 = *(const floatx4*)(p + 6 * 256);
        floatx4 h3 = *(const floatx4*)(p + 7 * 256);
        bx0 = cvt8p(l0, h0);
        bx1 = cvt8p(l1, h1);
        bx2 = cvt8p(l2, h2);
        if (q >= 2) {  // pad region: zeros, except k==112 gets the constant-1 feature (bias row)
            l3 = floatx4{(q == 2) ? 1.0f : 0.0f, 0.f, 0.f, 0.f};
            h3 = floatx4{0.f, 0.f, 0.f, 0.f};
        }
        bx3 = cvt8p(l3, h3);
    };

    auto gemm_store = [&](int e_, short8 bx0, short8 bx1, short8 bx2, short8 bx3) {
        // GEMM1: h^T tiles t=0..3 (hidden row t*16+q*4+r, col = edge c); b1 already folded in
        floatx4 acc[4];
#pragma unroll
        for (int t = 0; t < 4; ++t) {
            floatx4 a = {0.f, 0.f, 0.f, 0.f};
            a = __builtin_amdgcn_mfma_f32_16x16x32_bf16(w1f[0][t], bx0, a, 0, 0, 0);
            a = __builtin_amdgcn_mfma_f32_16x16x32_bf16(w1f[1][t], bx1, a, 0, 0, 0);
            a = __builtin_amdgcn_mfma_f32_16x16x32_bf16(w1f[2][t], bx2, a, 0, 0, 0);
            a = __builtin_amdgcn_mfma_f32_16x16x32_bf16(w1f[3][t], bx3, a, 0, 0, 0);
            acc[t] = a;
        }

        // relu + pack
        unsigned int pk[4][2];
#pragma unroll
        for (int t = 0; t < 4; ++t) {
            float v0 = fmaxf(acc[t][0], 0.f);
            float v1 = fmaxf(acc[t][1], 0.f);
            float v2 = fmaxf(acc[t][2], 0.f);
            float v3 = fmaxf(acc[t][3], 0.f);
            pk[t][0] = pack_bf(v0, v1);
            pk[t][1] = pack_bf(v2, v3);
        }

        // GEMM2: o^T = W2^T @ h^T ; B-frags from pk via ds_bpermute
        floatx4 acc2[2];
        acc2[0] = floatx4{0.f, 0.f, 0.f, 0.f};
        acc2[1] = floatx4{0.f, 0.f, 0.f, 0.f};
#pragma unroll
        for (int s2 = 0; s2 < 2; ++s2) {
            intx4 br;
#pragma unroll
            for (int m = 0; m < 4; ++m) {
                const int idx = (m >= 2) ? idx_hi : idx_lo;
                int vlo = __builtin_amdgcn_ds_bpermute(idx, (int)pk[2 * s2][m & 1]);
                int vhi = __builtin_amdgcn_ds_bpermute(idx, (int)pk[2 * s2 + 1][m & 1]);
                br[m] = want_hi_tile ? vhi : vlo;
            }
            short8 bB = __builtin_bit_cast(short8, br);
            acc2[0] = __builtin_amdgcn_mfma_f32_16x16x32_bf16(w2f[s2][0], bB, acc2[0], 0, 0, 0);
            acc2[1] = __builtin_amdgcn_mfma_f32_16x16x32_bf16(w2f[s2][1], bB, acc2[1], 0, 0, 0);
        }

        // store f32: lane holds out dims u*16+q*4+{0..3} of edge e_ -> 16B stores
#pragma unroll
        for (int u = 0; u < 2; ++u) {
            floatx4 o;
            o[0] = acc2[u][0] + b2v[u][0];
            o[1] = acc2[u][1] + b2v[u][1];
            o[2] = acc2[u][2] + b2v[u][2];
            o[3] = acc2[u][3] + b2v[u][3];
            *(floatx4*)(out + (size_t)e_ * 32 + u * 16 + q * 4) = o;
        }
    };

    // ---- pipelined main loop: DMA prefetch depth 1 (gathers), depth 2 (indices) ----
    int e = wid * 16 + c;
    int se = send[e], re = recv[e], be = batch[e];
    prefetch(e, se, re, be);
    {
        const int e1 = e + ESTRIDE;
        se = send[e1]; re = recv[e1]; be = batch[e1];
    }

    for (int k = 0; k < NITER - 1; ++k) {
        // drain only the 8 DMA loads of group k (3 newest = idx/stores may stay in flight)
        asm volatile("s_waitcnt vmcnt(3)" ::: "memory");
        __builtin_amdgcn_sched_barrier(0);

        short8 bx0, bx1, bx2, bx3;
        load_cvt(bx0, bx1, bx2, bx3);

        // FIFO regs consumed; make sure ds_reads retired before DMA can overwrite the buffer
        asm volatile("s_waitcnt lgkmcnt(0)" ::: "memory");
        __builtin_amdgcn_sched_barrier(0);

        const int en = e + ESTRIDE;
        prefetch(en, se, re, be);          // group k+1 -> FIFO (in flight across compute)
        int e2 = en + ESTRIDE;             // group k+2 indices
        if (e2 >= E_TOTAL) e2 = en;        // final trip: harmless in-bounds load, value unused
        se = send[e2]; re = recv[e2]; be = batch[e2];

        gemm_store(e, bx0, bx1, bx2, bx3); // compute group k under the prefetch
        e = en;
    }
    // peeled last group: nothing left to prefetch
    asm volatile("s_waitcnt vmcnt(3)" ::: "memory");
    __builtin_amdgcn_sched_barrier(0);
    {
        short8 bx0, bx1, bx2, bx3;
        load_cvt(bx0, bx1, bx2, bx3);
        gemm_store(e, bx0, bx1, bx2, bx3);
    }
}

extern "C" void kernel_launch(void* const* d_in, const int* in_sizes, int n_in,
                              void* d_out, int out_size, void* d_ws, size_t ws_size,
                              hipStream_t stream) {
    (void)in_sizes; (void)n_in; (void)out_size; (void)d_ws; (void)ws_size;
    const float* nodes = (const float*)d_in[0];
    const float* edges = (const float*)d_in[1];
    const float* gg    = (const float*)d_in[2];
    const int* send  = (const int*)d_in[3];
    const int* recv  = (const int*)d_in[4];
    const int* batch = (const int*)d_in[5];
    const float* W1 = (const float*)d_in[6];
    const float* b1 = (const float*)d_in[7];
    const float* W2 = (const float*)d_in[8];
    const float* b2 = (const float*)d_in[9];
    float* out = (float*)d_out;

    const int blocks = NWAVES / 4;   // 2500 blocks x 4 waves = 10000 waves, 10 groups each
    edge_mlp<<<blocks, 256, 0, stream>>>(nodes, edges, gg, send, recv, batch,
                                         W1, b1, W2, b2, out);
}

// Round 3
// 451.972 us; speedup vs baseline: 1.2554x; 1.1156x over previous
//
#include <hip/hip_runtime.h>

// EdgeBlock: out[e] = relu(concat(edges[e], nodes[send[e]], nodes[recv[e]], gg[batch[e]]) @ W1 + b1) @ W2 + b2
// E=1.6M, in=112, hidden=64, out=32. float32 tensors, int32 indices, float32 out.
//
// Strategy: transposed MFMA GEMMs, 16 edges per wave. W1/W2 bf16 fragments resident in VGPRs.
//   GEMM1: h^T = W1^T @ x^T over K=96 (edges|src|dst); the globals+bias term uses only 64 distinct
//   rows -> precomputed per block in f32 into LDS (bg[64][64] = gg@W1_u + b1) and loaded as the
//   GEMM1 accumulator init (batch sorted -> near-broadcast ds_reads).
//   GEMM2: o^T = W2^T @ h^T, B-frags via ds_bpermute. f32 epilogue, coalesced 16B stores.
//
// R3 changes vs R2 (which spilled): R2's launch_bounds(256,4) forced a 128-reg cap -> scratch
//   spills (VGPR=64 reported, SGPR=112, FETCH +95MB, WRITE +72MB of spill traffic). This version:
//   no min-occupancy clamp; register diet via bg-precompute (w1f 64->48 regs, 6 DMA ops/group,
//   12 MFMAs in GEMM1). Keeps the per-wave private LDS FIFO DMA prefetch (depth 1) + idx depth 2,
//   counted loop-top s_waitcnt vmcnt(2) so stores/idx stay in flight.

typedef __attribute__((ext_vector_type(8))) short short8;
typedef __attribute__((ext_vector_type(4))) float floatx4;
typedef __attribute__((ext_vector_type(8))) float floatx8;
typedef __attribute__((ext_vector_type(4))) int intx4;

#define E_TOTAL 1600000
#define NWAVES  10000               // 2500 blocks x 4 waves
#define NITER   10                  // NWAVES * NITER * 16 == E_TOTAL exactly
#define ESTRIDE (NWAVES * 16)

// pack two f32 -> (bf16(hi)<<16)|bf16(lo), round-half-up (+0x8000 then take high 16)
__device__ inline unsigned int pack_bf(float lo, float hi) {
    unsigned int a = __builtin_bit_cast(unsigned int, lo) + 0x8000u;
    unsigned int b = __builtin_bit_cast(unsigned int, hi) + 0x8000u;
    return __builtin_amdgcn_perm(b, a, 0x07060302);  // {b.hi16, a.hi16}
}

__device__ inline short8 cvt8(floatx8 f) {
    intx4 r;
    r[0] = (int)pack_bf(f[0], f[1]);
    r[1] = (int)pack_bf(f[2], f[3]);
    r[2] = (int)pack_bf(f[4], f[5]);
    r[3] = (int)pack_bf(f[6], f[7]);
    return __builtin_bit_cast(short8, r);
}

__device__ inline short8 cvt8p(floatx4 lo, floatx4 hi) {
    intx4 r;
    r[0] = (int)pack_bf(lo[0], lo[1]);
    r[1] = (int)pack_bf(lo[2], lo[3]);
    r[2] = (int)pack_bf(hi[0], hi[1]);
    r[3] = (int)pack_bf(hi[2], hi[3]);
    return __builtin_bit_cast(short8, r);
}

// async DMA: 16B per lane, per-lane GLOBAL src address, wave-uniform LDS dest (+lane*16 in HW)
__device__ inline void glds16(const void* g, void* l) {
    __builtin_amdgcn_global_load_lds(
        (const __attribute__((address_space(1))) void*)g,
        (__attribute__((address_space(3))) void*)l,
        16, 0, 0);
}

__global__ __launch_bounds__(256) void edge_mlp(
    const float* __restrict__ nodes,   // [50000][32]
    const float* __restrict__ edges,   // [E][32]
    const float* __restrict__ gg,      // [64][16]
    const int* __restrict__ send,
    const int* __restrict__ recv,
    const int* __restrict__ batch,
    const float* __restrict__ W1,      // [112][64]
    const float* __restrict__ b1,      // [64]
    const float* __restrict__ W2,      // [64][32]
    const float* __restrict__ b2,      // [32]
    float* __restrict__ out)           // [E][32]
{
    const int lane = threadIdx.x & 63;
    const int wid  = (int)((blockIdx.x * blockDim.x + threadIdx.x) >> 6);
    const int q = lane >> 4;     // quad: selects k-block of 8
    const int c = lane & 15;     // A-layout: row m; B-layout: col n; C-layout: col

    // per-wave private LDS FIFO: 6 slots of 1KB (slot s: lane L's 16B at s*1024 + L*16)
    __shared__ alignas(16) float fifo[4 * 1536];
    // per-graph precomputed accumulator init: bg[g][h] = sum_k gg[g][k]*W1[96+k][h] + b1[h]
    __shared__ alignas(16) float bg[64 * 64];
    float* wbuf = &fifo[(threadIdx.x >> 6) * 1536];

    // ---- W1^T A-fragments over K=96 (rows: edges 0..31 | src 32..63 | dst 64..95)
    //      w1f[s][t] elem j = W1[s*32+q*8+j][t*16+c]
    short8 w1f[3][4];
#pragma unroll
    for (int s = 0; s < 3; ++s)
#pragma unroll
        for (int t = 0; t < 4; ++t) {
            floatx8 f;
            const int hid = t * 16 + c;
#pragma unroll
            for (int j = 0; j < 8; ++j)
                f[j] = W1[(s * 32 + q * 8 + j) * 64 + hid];
            w1f[s][t] = cvt8(f);
        }
    // ---- W2^T A-fragments
    short8 w2f[2][2];
#pragma unroll
    for (int s2 = 0; s2 < 2; ++s2)
#pragma unroll
        for (int u = 0; u < 2; ++u) {
            floatx8 f;
            const int od = u * 16 + c;
#pragma unroll
            for (int j = 0; j < 8; ++j)
                f[j] = W2[(s2 * 32 + q * 8 + j) * 32 + od];
            w2f[s2][u] = cvt8(f);
        }
    // ---- b2 (f32 epilogue), C-layout row = u*16 + q*4 + r
    float b2v[2][4];
#pragma unroll
    for (int u = 0; u < 2; ++u)
#pragma unroll
        for (int r = 0; r < 4; ++r) b2v[u][r] = b2[u * 16 + q * 4 + r];

    // bpermute source-lane byte indices for the C->B quad shuffle
    const int idx_lo = (((q & 1) * 2) * 16 + c) * 4;  // m = 0,1
    const int idx_hi = idx_lo + 64;                   // m = 2,3
    const bool want_hi_tile = (q >= 2);

    auto prefetch = [&](int eb, int s_, int r_) {
        glds16(edges + (size_t)eb * 32 + q * 8,      wbuf + 0 * 256);
        glds16(edges + (size_t)eb * 32 + q * 8 + 4,  wbuf + 1 * 256);
        glds16(nodes + (size_t)s_ * 32 + q * 8,      wbuf + 2 * 256);
        glds16(nodes + (size_t)s_ * 32 + q * 8 + 4,  wbuf + 3 * 256);
        glds16(nodes + (size_t)r_ * 32 + q * 8,      wbuf + 4 * 256);
        glds16(nodes + (size_t)r_ * 32 + q * 8 + 4,  wbuf + 5 * 256);
    };

    // ---- prologue: idx0 -> DMA group 0 -> idx1 -> bg precompute -> barrier ----
    int e = wid * 16 + c;
    int be_c;                      // batch of current group (needed at compute time)
    {
        const int se0 = send[e], re0 = recv[e];
        be_c = batch[e];
        prefetch(e, se0, re0);
    }
    int se_n, re_n, be_n;          // indices of next group
    {
        const int e1 = e + ESTRIDE;
        se_n = send[e1]; re_n = recv[e1]; be_n = batch[e1];
    }

    // bg: 256 threads x 16 entries each (graph g0 = tid>>2, h-range hb..hb+15), pure f32
    {
        const int tid = threadIdx.x;
        const int g0 = tid >> 2;
        const int hb = (tid & 3) * 16;
        floatx4 a0 = *(const floatx4*)(b1 + hb);
        floatx4 a1 = *(const floatx4*)(b1 + hb + 4);
        floatx4 a2 = *(const floatx4*)(b1 + hb + 8);
        floatx4 a3 = *(const floatx4*)(b1 + hb + 12);
#pragma unroll
        for (int k = 0; k < 16; ++k) {
            const float uk = gg[g0 * 16 + k];
            const float* wr = W1 + (96 + k) * 64 + hb;
            floatx4 w0 = *(const floatx4*)(wr);
            floatx4 w1v = *(const floatx4*)(wr + 4);
            floatx4 w2v = *(const floatx4*)(wr + 8);
            floatx4 w3 = *(const floatx4*)(wr + 12);
#pragma unroll
            for (int m = 0; m < 4; ++m) {
                a0[m] += uk * w0[m]; a1[m] += uk * w1v[m];
                a2[m] += uk * w2v[m]; a3[m] += uk * w3[m];
            }
        }
        *(floatx4*)(bg + g0 * 64 + hb)      = a0;
        *(floatx4*)(bg + g0 * 64 + hb + 4)  = a1;
        *(floatx4*)(bg + g0 * 64 + hb + 8)  = a2;
        *(floatx4*)(bg + g0 * 64 + hb + 12) = a3;
    }
    __syncthreads();   // bg visible; also drains prologue DMA (group 0 ready)

    // ---- main loop: NITER-1 pipelined iters + peeled last ----
    for (int k = 0; k < NITER - 1; ++k) {
        // drain this group's 6 DMA loads; idx loads (old) drain too; 2 stores may stay in flight
        asm volatile("s_waitcnt vmcnt(2)" ::: "memory");

        const float* p = wbuf + lane * 4;
        floatx4 l0 = *(const floatx4*)(p + 0 * 256);
        floatx4 h0 = *(const floatx4*)(p + 1 * 256);
        floatx4 l1 = *(const floatx4*)(p + 2 * 256);
        floatx4 h1 = *(const floatx4*)(p + 3 * 256);
        floatx4 l2 = *(const floatx4*)(p + 4 * 256);
        floatx4 h2 = *(const floatx4*)(p + 5 * 256);
        short8 bx0 = cvt8p(l0, h0);
        short8 bx1 = cvt8p(l1, h1);
        short8 bx2 = cvt8p(l2, h2);

        // FIFO reads retired -> safe to overwrite slots with next group's DMA
        asm volatile("s_waitcnt lgkmcnt(0)" ::: "memory");

        const int e_cur = e;
        const int be_use = be_c;
        const int en = e + ESTRIDE;
        prefetch(en, se_n, re_n);          // group k+1 -> FIFO, in flight across compute
        be_c = be_n;
        int e2 = en + ESTRIDE;             // group k+2 indices (clamped on final trip)
        if (e2 >= E_TOTAL) e2 = en;
        se_n = send[e2]; re_n = recv[e2]; be_n = batch[e2];
        e = en;
        // pin: stores/compute below must not hoist above the glds+idx clump (vmcnt count proof)
        __builtin_amdgcn_sched_barrier(0);

        // GEMM1: acc init = bg[batch] (u-term + b1, f32 exact), then 3 K-steps of bf16 MFMA
        floatx4 acc[4];
#pragma unroll
        for (int t = 0; t < 4; ++t) {
            floatx4 a = *(const floatx4*)(bg + be_use * 64 + t * 16 + q * 4);
            a = __builtin_amdgcn_mfma_f32_16x16x32_bf16(w1f[0][t], bx0, a, 0, 0, 0);
            a = __builtin_amdgcn_mfma_f32_16x16x32_bf16(w1f[1][t], bx1, a, 0, 0, 0);
            a = __builtin_amdgcn_mfma_f32_16x16x32_bf16(w1f[2][t], bx2, a, 0, 0, 0);
            acc[t] = a;
        }

        // relu + pack
        unsigned int pk[4][2];
#pragma unroll
        for (int t = 0; t < 4; ++t) {
            float v0 = fmaxf(acc[t][0], 0.f);
            float v1 = fmaxf(acc[t][1], 0.f);
            float v2 = fmaxf(acc[t][2], 0.f);
            float v3 = fmaxf(acc[t][3], 0.f);
            pk[t][0] = pack_bf(v0, v1);
            pk[t][1] = pack_bf(v2, v3);
        }

        // GEMM2: o^T = W2^T @ h^T ; B-frags from pk via ds_bpermute
        floatx4 acc2[2];
        acc2[0] = floatx4{0.f, 0.f, 0.f, 0.f};
        acc2[1] = floatx4{0.f, 0.f, 0.f, 0.f};
#pragma unroll
        for (int s2 = 0; s2 < 2; ++s2) {
            intx4 br;
#pragma unroll
            for (int m = 0; m < 4; ++m) {
                const int idx = (m >= 2) ? idx_hi : idx_lo;
                int vlo = __builtin_amdgcn_ds_bpermute(idx, (int)pk[2 * s2][m & 1]);
                int vhi = __builtin_amdgcn_ds_bpermute(idx, (int)pk[2 * s2 + 1][m & 1]);
                br[m] = want_hi_tile ? vhi : vlo;
            }
            short8 bB = __builtin_bit_cast(short8, br);
            acc2[0] = __builtin_amdgcn_mfma_f32_16x16x32_bf16(w2f[s2][0], bB, acc2[0], 0, 0, 0);
            acc2[1] = __builtin_amdgcn_mfma_f32_16x16x32_bf16(w2f[s2][1], bB, acc2[1], 0, 0, 0);
        }

        // store f32: lane holds out dims u*16+q*4+{0..3} of edge e_cur -> 16B stores
#pragma unroll
        for (int u = 0; u < 2; ++u) {
            floatx4 o;
            o[0] = acc2[u][0] + b2v[u][0];
            o[1] = acc2[u][1] + b2v[u][1];
            o[2] = acc2[u][2] + b2v[u][2];
            o[3] = acc2[u][3] + b2v[u][3];
            *(floatx4*)(out + (size_t)e_cur * 32 + u * 16 + q * 4) = o;
        }
    }

    // ---- peeled last group: nothing left to prefetch ----
    {
        asm volatile("s_waitcnt vmcnt(2)" ::: "memory");
        const float* p = wbuf + lane * 4;
        floatx4 l0 = *(const floatx4*)(p + 0 * 256);
        floatx4 h0 = *(const floatx4*)(p + 1 * 256);
        floatx4 l1 = *(const floatx4*)(p + 2 * 256);
        floatx4 h1 = *(const floatx4*)(p + 3 * 256);
        floatx4 l2 = *(const floatx4*)(p + 4 * 256);
        floatx4 h2 = *(const floatx4*)(p + 5 * 256);
        short8 bx0 = cvt8p(l0, h0);
        short8 bx1 = cvt8p(l1, h1);
        short8 bx2 = cvt8p(l2, h2);

        floatx4 acc[4];
#pragma unroll
        for (int t = 0; t < 4; ++t) {
            floatx4 a = *(const floatx4*)(bg + be_c * 64 + t * 16 + q * 4);
            a = __builtin_amdgcn_mfma_f32_16x16x32_bf16(w1f[0][t], bx0, a, 0, 0, 0);
            a = __builtin_amdgcn_mfma_f32_16x16x32_bf16(w1f[1][t], bx1, a, 0, 0, 0);
            a = __builtin_amdgcn_mfma_f32_16x16x32_bf16(w1f[2][t], bx2, a, 0, 0, 0);
            acc[t] = a;
        }
        unsigned int pk[4][2];
#pragma unroll
        for (int t = 0; t < 4; ++t) {
            float v0 = fmaxf(acc[t][0], 0.f);
            float v1 = fmaxf(acc[t][1], 0.f);
            float v2 = fmaxf(acc[t][2], 0.f);
            float v3 = fmaxf(acc[t][3], 0.f);
            pk[t][0] = pack_bf(v0, v1);
            pk[t][1] = pack_bf(v2, v3);
        }
        floatx4 acc2[2];
        acc2[0] = floatx4{0.f, 0.f, 0.f, 0.f};
        acc2[1] = floatx4{0.f, 0.f, 0.f, 0.f};
#pragma unroll
        for (int s2 = 0; s2 < 2; ++s2) {
            intx4 br;
#pragma unroll
            for (int m = 0; m < 4; ++m) {
                const int idx = (m >= 2) ? idx_hi : idx_lo;
                int vlo = __builtin_amdgcn_ds_bpermute(idx, (int)pk[2 * s2][m & 1]);
                int vhi = __builtin_amdgcn_ds_bpermute(idx, (int)pk[2 * s2 + 1][m & 1]);
                br[m] = want_hi_tile ? vhi : vlo;
            }
            short8 bB = __builtin_bit_cast(short8, br);
            acc2[0] = __builtin_amdgcn_mfma_f32_16x16x32_bf16(w2f[s2][0], bB, acc2[0], 0, 0, 0);
            acc2[1] = __builtin_amdgcn_mfma_f32_16x16x32_bf16(w2f[s2][1], bB, acc2[1], 0, 0, 0);
        }
#pragma unroll
        for (int u = 0; u < 2; ++u) {
            floatx4 o;
            o[0] = acc2[u][0] + b2v[u][0];
            o[1] = acc2[u][1] + b2v[u][1];
            o[2] = acc2[u][2] + b2v[u][2];
            o[3] = acc2[u][3] + b2v[u][3];
            *(floatx4*)(out + (size_t)e * 32 + u * 16 + q * 4) = o;
        }
    }
}

extern "C" void kernel_launch(void* const* d_in, const int* in_sizes, int n_in,
                              void* d_out, int out_size, void* d_ws, size_t ws_size,
                              hipStream_t stream) {
    (void)in_sizes; (void)n_in; (void)out_size; (void)d_ws; (void)ws_size;
    const float* nodes = (const float*)d_in[0];
    const float* edges = (const float*)d_in[1];
    const float* gg    = (const float*)d_in[2];
    const int* send  = (const int*)d_in[3];
    const int* recv  = (const int*)d_in[4];
    const int* batch = (const int*)d_in[5];
    const float* W1 = (const float*)d_in[6];
    const float* b1 = (const float*)d_in[7];
    const float* W2 = (const float*)d_in[8];
    const float* b2 = (const float*)d_in[9];
    float* out = (float*)d_out;

    const int blocks = NWAVES / 4;   // 2500 blocks x 4 waves = 10000 waves, 10 groups each
    edge_mlp<<<blocks, 256, 0, stream>>>(nodes, edges, gg, send, recv, batch,
                                         W1, b1, W2, b2, out);
}